// Round 10
// baseline (444.550 us; speedup 1.0000x reference)
//
#include <hip/hip_runtime.h>

// ---------------------------------------------------------------------------
// Attention_1752346656894: 3D-window attention w/ dynamic position bias.
// R16 == R15 re-run verbatim (bench died with the same infra error as R11's
// round; R15's theory is untested). Audited for deadlock/race before
// resubmit: uniform-flow barriers only; double-buffer parity protected by
// end-of-kt barrier + vmcnt(0) drain; stageV addressing verified linear.
// R15: occupancy attack. lVt (full 32x512 V^T, 33.3KB -> 4 blocks/CU)
// replaced by DOUBLE-BUFFERED per-kt tile lVt2[2][32][136] = 17.4KB ->
// 8 blocks/CU (100% wave cap at 64 VGPR). Staging = 32 rows x 256B via
// width-4 global_load_lds (8/wave) from the L2-hot V^T page, prefetched for
// kt+1 before kt's compute; 1 barrier/kt. K loads in R10's per-t form (no
// spill). setprio kept. Keeps: XCD-chunked swizzle, swapped QK^T, in-reg P
// repack, base-2 softmax, defer-max, fused prep, gload_lds GEMMs, in-place
// V^T page transpose.
// ---------------------------------------------------------------------------

typedef __bf16 bf16;
typedef __bf16 bf16x4 __attribute__((ext_vector_type(4)));
typedef __bf16 bf16x8 __attribute__((ext_vector_type(8)));
typedef float  f32x4  __attribute__((ext_vector_type(4)));
typedef unsigned int u32;
typedef u32 u32x4v __attribute__((ext_vector_type(4)));

#define DIMC   384
#define HEADS  12
#define HD     32
#define NTOK   512
#define NWIN   64
#define LTAB   3375      // 15^3
#define LPAD   3392      // padded to 16B multiple (bf16)
#define PD     24
#define LOG2E  1.4426950408889634f
#define QPRE   (0.17677669529663687f * LOG2E)   // 32^-0.5 * log2(e)
#define VSTR2  136       // per-kt V^T tile row stride (bf16): 128+8 -> 272B
#define VBUF   (32 * VSTR2)   // 4352 elements per buffer

#define SZ_WQT  884736ll
#define SZ_WPT  294912ll
#define SZ_POST 81408ll        // bf16 [12][3392]
#define SZ_FLAG 256ll
#define SZ_B2   6291456ll      // bf16 [12][512][512]  ([h][q][k])
#define SZ_MT   4194304ll      // legacy region (unused, keeps layout)
#define SZ_QKV  25165824ll
#define WS_SMALL 102236160ull
#define WS_BIG   112410368ull

// prep kernel block ranges
#define NB_XC   12288   // 32768*384/4/256
#define NB_WQT  1728    // 384*1152/256
#define NB_WPT  576     // 384*384/256
#define NB_MSK  256
#define NB_POS  14      // ceil(3375/256)
#define NB_PREP (NB_XC + NB_WQT + NB_WPT + NB_MSK + NB_POS)

#define NB_ATTN (HEADS * NWIN * 4)   // 3072, divisible by 8

__device__ inline u32 cvtpk(float lo, float hi) {
    u32 r;
    asm("v_cvt_pk_bf16_f32 %0, %1, %2" : "=v"(r) : "v"(lo), "v"(hi));
    return r;
}
__device__ inline void plswap32(u32& a, u32& b) {
    asm("v_permlane32_swap_b32 %0, %1" : "+v"(a), "+v"(b));
}
__device__ inline void plswap16(u32& a, u32& b) {
    asm("v_permlane16_swap_b32 %0, %1" : "+v"(a), "+v"(b));
}
__device__ inline float ex2(float x) {
#if __has_builtin(__builtin_amdgcn_exp2f)
    return __builtin_amdgcn_exp2f(x);
#else
    float r; asm("v_exp_f32 %0, %1" : "=v"(r) : "v"(x)); return r;
#endif
}
__device__ inline void gload_lds16(const void* g, void* l) {
    __builtin_amdgcn_global_load_lds(
        (const __attribute__((address_space(1))) void*)g,
        (__attribute__((address_space(3))) void*)l, 16, 0, 0);
}
__device__ inline void gload_lds4(const void* g, void* l) {
    __builtin_amdgcn_global_load_lds(
        (const __attribute__((address_space(1))) void*)g,
        (__attribute__((address_space(3))) void*)l, 4, 0, 0);
}

// ---------------------------------------------------------------------------
__device__ inline void ln_relu24(const float* x, const float* __restrict__ g,
                                 const float* __restrict__ b, float* y)
{
    float mean = 0.f;
#pragma unroll
    for (int j = 0; j < PD; j++) mean += x[j];
    mean *= (1.f / PD);
    float var = 0.f;
#pragma unroll
    for (int j = 0; j < PD; j++) { float d = x[j] - mean; var += d * d; }
    var *= (1.f / PD);
    float inv = rsqrtf(var + 1e-5f);
#pragma unroll
    for (int j = 0; j < PD; j++) {
        float t = (x[j] - mean) * inv * g[j] + b[j];
        y[j] = t > 0.f ? t : 0.f;
    }
}

// ---------------------------------------------------------------------------
// Fused preprocessing: [xcast | qkv_w^T | proj_w^T | mask_detect | pos_mlp]
__global__ __launch_bounds__(256) void prep_kernel(
    const float* __restrict__ x,
    const float* __restrict__ qkv_w, const float* __restrict__ proj_w,
    const float* __restrict__ mask,
    const float* __restrict__ pw,  const float* __restrict__ pb,
    const float* __restrict__ g1,  const float* __restrict__ b1,
    const float* __restrict__ w1,  const float* __restrict__ bb1,
    const float* __restrict__ g2,  const float* __restrict__ b2,
    const float* __restrict__ w2,  const float* __restrict__ bb2,
    const float* __restrict__ g3,  const float* __restrict__ b3,
    const float* __restrict__ w3,  const float* __restrict__ bb3,
    bf16* __restrict__ xb, bf16* __restrict__ wqT, bf16* __restrict__ wpT,
    int* __restrict__ flag, bf16* __restrict__ posTg)
{
    const int tid = threadIdx.x;
    int bx = blockIdx.x;

    if (bx < NB_XC) {                       // x fp32 -> bf16
        const int i = bx * 256 + tid;
        const f32x4 v = *(const f32x4*)(x + (size_t)i * 4);
        bf16x4 o;
#pragma unroll
        for (int j = 0; j < 4; j++) o[j] = (bf16)v[j];
        *(bf16x4*)(xb + (size_t)i * 4) = o;
        return;
    }
    bx -= NB_XC;
    if (bx < NB_WQT) {                      // qkv_w [384][1152] -> [1152][384] bf16
        const int idx = bx * 256 + tid;
        const int n = idx / 384, k = idx - n * 384;
        wqT[idx] = (bf16)qkv_w[(size_t)k * 1152 + n];
        return;
    }
    bx -= NB_WQT;
    if (bx < NB_WPT) {                      // proj_w [384][384] -> transposed bf16
        const int idx = bx * 256 + tid;
        const int n = idx / 384, k = idx - n * 384;
        wpT[idx] = (bf16)proj_w[(size_t)k * 384 + n];
        return;
    }
    bx -= NB_WPT;
    if (bx < NB_MSK) {                      // mask nonzero detect
        const int i = bx * 256 + tid;
        const float* p = mask + (size_t)i * 32;
        float s = 0.f;
#pragma unroll
        for (int j = 0; j < 32; j++) s += fabsf(p[j]);
        if (!(s == 0.f)) atomicOr(flag, 1);
        return;
    }
    bx -= NB_MSK;
    {                                       // pos MLP (output *LOG2E)
        const int l = bx * 256 + tid;
        if (l >= LTAB) return;
        const int ih = l / 225, iw = (l / 15) % 15, id = l % 15;
        const float c0 = (float)(ih - 7), c1 = (float)(iw - 7), c2 = (float)(id - 7);
        float xx[PD], y[PD];
#pragma unroll
        for (int j = 0; j < PD; j++)
            xx[j] = c0 * pw[j] + c1 * pw[PD + j] + c2 * pw[2 * PD + j] + pb[j];
        ln_relu24(xx, g1, b1, y);
#pragma unroll
        for (int j = 0; j < PD; j++) {
            float a = bb1[j];
#pragma unroll
            for (int i = 0; i < PD; i++) a += y[i] * w1[i * PD + j];
            xx[j] = a;
        }
        ln_relu24(xx, g2, b2, y);
#pragma unroll
        for (int j = 0; j < PD; j++) {
            float a = bb2[j];
#pragma unroll
            for (int i = 0; i < PD; i++) a += y[i] * w2[i * PD + j];
            xx[j] = a;
        }
        ln_relu24(xx, g3, b3, y);
#pragma unroll
        for (int hh = 0; hh < HEADS; hh++) {
            float a = bb3[hh];
#pragma unroll
            for (int i = 0; i < PD; i++) a += y[i] * w3[i * HEADS + hh];
            posTg[hh * LPAD + l] = (bf16)(a * LOG2E);
        }
    }
}

// ---------------------------------------------------------------------------
// bias2[h][q][k] = pos-bias (already *LOG2E). Coalesced writes along k.
__global__ __launch_bounds__(256) void bias2_build_kernel(
    const bf16* __restrict__ posTg, bf16* __restrict__ bias2)
{
    int idx = blockIdx.x * 256 + threadIdx.x;   // 12*512*512 exact grid
    int h = idx >> 18;
    int q = (idx >> 9) & 511;
    int m = idx & 511;
    int dh = (q >> 6) - (m >> 6) + 7;
    int dw = ((q >> 3) & 7) - ((m >> 3) & 7) + 7;
    int dd = (q & 7) - (m & 7) + 7;
    bias2[idx] = posTg[h * LPAD + dh * 225 + dw * 15 + dd];
}

// ---------------------------------------------------------------------------
// In-place per-(b,h) page transpose: V[page][512][32] -> V^T[page][32][512].
__global__ __launch_bounds__(256) void vt_inplace_kernel(bf16* __restrict__ V)
{
    __shared__ __align__(16) bf16 tile[32 * 520];
    bf16* base = V + (size_t)blockIdx.x * (NTOK * HD);
    const int tid = threadIdx.x;
    const int nq = tid >> 2;            // 0..63
    const int c4 = tid & 3;
    const int d0 = c4 * 8;
#pragma unroll
    for (int it = 0; it < 8; it++) {
        const int n = nq + it * 64;
        bf16x8 v = *(const bf16x8*)(base + n * HD + d0);
#pragma unroll
        for (int j = 0; j < 8; j++) {   // staggered to break d0-group conflicts
            const int jj = (j + (c4 << 1)) & 7;
            tile[(d0 + jj) * 520 + n] = v[jj];
        }
    }
    __syncthreads();
#pragma unroll
    for (int it = 0; it < 8; it++) {
        const int o = it * 2048 + tid * 8;
        const int d = o >> 9, n = o & 511;
        bf16x8 w = *(const bf16x8*)(tile + d * 520 + n);
        *(bf16x8*)(base + d * NTOK + n) = w;
    }
}

// ---------------------------------------------------------------------------
// GEMM: C[M][N] = A[M][K] @ Bt[N][K]^T + bias. 128x128 tile, BK=64.
template <int MODE>
__global__ __launch_bounds__(256) void gemm_bt(
    const bf16* __restrict__ A, const bf16* __restrict__ Bt,
    const float* __restrict__ bias,
    bf16* __restrict__ O0, bf16* __restrict__ O1, bf16* __restrict__ O2,
    float* __restrict__ Of, int K, int N)
{
    __shared__ __align__(16) bf16 lA[128 * 64];
    __shared__ __align__(16) bf16 lB[128 * 64];
    const int row0 = blockIdx.x * 128;
    const int col0 = blockIdx.y * 128;
    const int tid  = threadIdx.x;
    const int lane = tid & 63;
    const int wave = tid >> 6;
    const int r0   = (wave >> 1) * 64;
    const int c0   = (wave & 1) * 64;
    const int lrow = lane & 15;
    const int lch  = lane >> 4;

    f32x4 acc[4][4];
    const f32x4 zero4 = {0.f, 0.f, 0.f, 0.f};
#pragma unroll
    for (int i = 0; i < 4; i++)
#pragma unroll
        for (int j = 0; j < 4; j++) acc[i][j] = zero4;

    for (int kt = 0; kt < K; kt += 64) {
        __syncthreads();
#pragma unroll
        for (int it = 0; it < 4; it++) {
            const int c  = tid + it * 256;
            const int rr = c >> 3;
            const int cc = (c & 7) * 8;
            bf16* la = lA + (size_t)(it * 256 + wave * 64) * 8;
            bf16* lb = lB + (size_t)(it * 256 + wave * 64) * 8;
            gload_lds16(A  + (size_t)(row0 + rr) * K + kt + cc, la);
            gload_lds16(Bt + (size_t)(col0 + rr) * K + kt + cc, lb);
        }
        __syncthreads();
#pragma unroll
        for (int kk = 0; kk < 64; kk += 32) {
            bf16x8 af[4], bfr[4];
#pragma unroll
            for (int i = 0; i < 4; i++)
                af[i] = *(const bf16x8*)(lA + (r0 + i * 16 + lrow) * 64 + kk + lch * 8);
#pragma unroll
            for (int j = 0; j < 4; j++)
                bfr[j] = *(const bf16x8*)(lB + (c0 + j * 16 + lrow) * 64 + kk + lch * 8);
#pragma unroll
            for (int i = 0; i < 4; i++)
#pragma unroll
                for (int j = 0; j < 4; j++)
                    acc[i][j] = __builtin_amdgcn_mfma_f32_16x16x32_bf16(af[i], bfr[j], acc[i][j], 0, 0, 0);
        }
    }

#pragma unroll
    for (int i = 0; i < 4; i++) {
#pragma unroll
        for (int j = 0; j < 4; j++) {
#pragma unroll
            for (int r = 0; r < 4; r++) {
                const int mrow = row0 + r0 + i * 16 + lch * 4 + r;
                const int ncol = col0 + c0 + j * 16 + lrow;
                const float v = acc[i][j][r] + bias[ncol];
                if (MODE == 0) {
                    const int t    = ncol >= 768 ? 2 : (ncol >= 384 ? 1 : 0);
                    const int rem2 = ncol - t * 384;
                    const int hh   = rem2 >> 5;
                    const int dd   = rem2 & 31;
                    const int bwin = mrow >> 9;
                    const int n    = mrow & 511;
                    bf16* dst = (t == 0) ? O0 : ((t == 1) ? O1 : O2);
                    const float vv = (t == 0) ? v * QPRE : v;   // Q prescale (log2 domain)
                    dst[(size_t)((bwin * HEADS + hh) * NTOK + n) * HD + dd] = (bf16)vv;
                } else {
                    Of[(size_t)mrow * N + ncol] = v;
                }
            }
        }
    }
}

// ---------------------------------------------------------------------------
// Flash attention, swapped-QK^T, P repack in regs, XCD-chunked swizzle.
// Double-buffered per-kt V^T LDS tile (17.4KB -> 8 blocks/CU).
template <int BIG>
__global__ __launch_bounds__(256, 4) void attn_kernel(
    const bf16* __restrict__ Qg, const bf16* __restrict__ Kg,
    const bf16* __restrict__ Vtg, const bf16* __restrict__ posTg,
    const float* __restrict__ maskg, const bf16* __restrict__ bias2,
    const int* __restrict__ mflag, bf16* __restrict__ Og)
{
    __shared__ __align__(16) bf16 lVt2[2 * VBUF];          // 17,408 B
    __shared__ __align__(16) bf16 lPos[BIG ? 16 : LPAD];

    // XCD-chunked swizzle (bijective: 3072 % 8 == 0)
    const int idx = (blockIdx.x & 7) * (NB_ATTN / 8) + (blockIdx.x >> 3);
    const int h   = idx >> 8;
    const int rem = idx & 255;
    const int b   = rem >> 2;
    const int qt  = rem & 3;
    const int g   = b & 7;
    const int tid = threadIdx.x;
    const int lane = tid & 63;
    const int wave = tid >> 6;
    const int lrow = lane & 15;
    const int lch  = lane >> 4;
    const int msk  = *mflag;

    const bf16* Qp  = Qg  + (size_t)(b * HEADS + h) * NTOK * HD;
    const bf16* Kp  = Kg  + (size_t)(b * HEADS + h) * NTOK * HD;
    const bf16* Vtp = Vtg + (size_t)(b * HEADS + h) * NTOK * HD;   // [32][512]
    const float* Mp = maskg + (size_t)g * NTOK * NTOK;
    const bf16* B2p = bias2 + (size_t)h * NTOK * NTOK;             // [q][k]

    // stage one kt's V^T columns (32 rows x 256B) into buffer bb.
    // width-4 gload_lds: 64 lanes x 4B = one 256B row per instruction.
    auto stageV = [&](int bb, int kt2) {
#pragma unroll
        for (int rr = 0; rr < 8; rr++) {
            const int d = wave * 8 + rr;
            gload_lds4(Vtp + (size_t)d * NTOK + kt2 * 128 + lane * 2,
                       lVt2 + bb * VBUF + d * VSTR2);
        }
    };

    stageV(0, 0);
    if (!BIG) {
        const uint4* src = (const uint4*)(posTg + h * LPAD);
        for (int i = tid; i < LPAD * 2 / 16; i += 256)
            ((uint4*)lPos)[i] = src[i];
    }
    __syncthreads();

    const int qbase = qt * 128 + wave * 32;

    bf16x8 qf[2];
#pragma unroll
    for (int t = 0; t < 2; t++)
        qf[t] = *(const bf16x8*)(Qp + (size_t)(qbase + t * 16 + lrow) * HD + lch * 8);

    int qc0[2] = {0, 0}, qc1[2] = {0, 0}, qc2[2] = {0, 0};
    if (!BIG) {
#pragma unroll
        for (int t = 0; t < 2; t++) {
            const int q = qbase + t * 16 + lrow;
            qc0[t] = q >> 6; qc1[t] = (q >> 3) & 7; qc2[t] = q & 7;
        }
    }

    float m_i[2] = {-1e30f, -1e30f};
    float l_i[2] = {0.f, 0.f};
    f32x4 oacc[2][2];
    const f32x4 zero4 = {0.f, 0.f, 0.f, 0.f};
    oacc[0][0] = zero4; oacc[0][1] = zero4;
    oacc[1][0] = zero4; oacc[1][1] = zero4;

    for (int kt = 0; kt < 4; kt++) {
        // prefetch next kt's V^T tile into the other buffer (async; the
        // barrier at loop end drains it before it is read)
        if (kt < 3) stageV((kt + 1) & 1, kt + 1);

        bf16x8 apc[2][4];   // packed P, A-fragment layout, per q-tile per 32-k chunk
        float alr[2];
        bool doresc[2];

#pragma unroll
        for (int t = 0; t < 2; t++) {
            const int qrow = qbase + t * 16 + lrow;
            f32x4 sf[8];

            // bias prefetch (BIG): 8 x bf16x4, vectorized along k
            bf16x4 bld[8];
            if (BIG) {
                const bf16* brow = B2p + (size_t)qrow * NTOK + kt * 128 + lch * 4;
#pragma unroll
                for (int ct = 0; ct < 8; ct++)
                    bld[ct] = *(const bf16x4*)(brow + ct * 16);
            }

            // S^T = K @ Q^T  (C layout: row = k-token, col = q = lrow)
            __builtin_amdgcn_s_setprio(1);
#pragma unroll
            for (int ct = 0; ct < 8; ct++) {
                bf16x8 kf = *(const bf16x8*)(Kp + (size_t)(kt * 128 + ct * 16 + lrow) * HD + lch * 8);
                sf[ct] = __builtin_amdgcn_mfma_f32_16x16x32_bf16(kf, qf[t], zero4, 0, 0, 0);
            }
            __builtin_amdgcn_s_setprio(0);

            if (BIG) {
#pragma unroll
                for (int ct = 0; ct < 8; ct++)
#pragma unroll
                    for (int r = 0; r < 4; r++)
                        sf[ct][r] += (float)bld[ct][r];
            } else {
#pragma unroll
                for (int ct = 0; ct < 8; ct++) {
#pragma unroll
                    for (int r = 0; r < 4; r++) {
                        const int k = kt * 128 + ct * 16 + lch * 4 + r;
                        const int rpi = (qc0[t] - (k >> 6) + 7) * 225
                                      + (qc1[t] - ((k >> 3) & 7) + 7) * 15
                                      + (qc2[t] - (k & 7) + 7);
                        sf[ct][r] += (float)lPos[rpi];
                    }
                }
            }
            if (msk) {
                const float* mrow = Mp + (size_t)qrow * NTOK + kt * 128 + lch * 4;
#pragma unroll
                for (int ct = 0; ct < 8; ct++) {
                    f32x4 mv = *(const f32x4*)(mrow + ct * 16);
#pragma unroll
                    for (int r = 0; r < 4; r++)
                        sf[ct][r] = fmaf(mv[r], LOG2E, sf[ct][r]);
                }
            }

            // online softmax (base 2): in-lane tree + 2 cross-lane hops
            float px[8];
#pragma unroll
            for (int ct = 0; ct < 8; ct++)
                px[ct] = fmaxf(fmaxf(sf[ct][0], sf[ct][1]), fmaxf(sf[ct][2], sf[ct][3]));
            float mx = fmaxf(fmaxf(fmaxf(px[0], px[1]), fmaxf(px[2], px[3])),
                             fmaxf(fmaxf(px[4], px[5]), fmaxf(px[6], px[7])));
            mx = fmaxf(mx, __shfl_xor(mx, 16));
            mx = fmaxf(mx, __shfl_xor(mx, 32));

            // T13 defer-max: keep stale m while growth <= 8 (p <= 2^8, bf16-ok)
            if (__all(mx <= m_i[t] + 8.f)) {
                alr[t] = 1.f;
                doresc[t] = false;
            } else {
                const float mnew = fmaxf(m_i[t], mx);
                alr[t] = ex2(m_i[t] - mnew);
                m_i[t] = mnew;
                doresc[t] = true;
            }

            float s0 = 0.f, s1 = 0.f;
#pragma unroll
            for (int ct = 0; ct < 8; ct++) {
#pragma unroll
                for (int r = 0; r < 4; r++)
                    sf[ct][r] = ex2(sf[ct][r] - m_i[t]);
                s0 += sf[ct][0] + sf[ct][1];
                s1 += sf[ct][2] + sf[ct][3];
            }
            float ls = s0 + s1;
            ls += __shfl_xor(ls, 16);
            ls += __shfl_xor(ls, 32);
            l_i[t] = l_i[t] * alr[t] + ls;

            // pack P -> A-fragments, fully in registers (cvt_pk + permlane;
            // distinct operands — proven since R7).
#pragma unroll
            for (int c2 = 0; c2 < 4; c2++) {
                u32 a01 = cvtpk(sf[2 * c2][0],     sf[2 * c2][1]);
                u32 a23 = cvtpk(sf[2 * c2][2],     sf[2 * c2][3]);
                u32 b01 = cvtpk(sf[2 * c2 + 1][0], sf[2 * c2 + 1][1]);
                u32 b23 = cvtpk(sf[2 * c2 + 1][2], sf[2 * c2 + 1][3]);
                plswap32(a01, b01); plswap16(a01, b01);
                plswap32(a23, b23); plswap16(a23, b23);
                u32x4v w; w[0] = a01; w[1] = a23; w[2] = b01; w[3] = b23;
                apc[t][c2] = __builtin_bit_cast(bf16x8, w);
            }
        }

        // rescale O by alpha (wave-uniform skip when deferred)
#pragma unroll
        for (int t = 0; t < 2; t++) {
            if (doresc[t]) {
#pragma unroll
                for (int r = 0; r < 4; r++) {
                    const float a = __shfl(alr[t], lch * 4 + r);
                    oacc[t][0][r] *= a;
                    oacc[t][1][r] *= a;
                }
            }
        }

        // P @ V from current per-kt LDS tile
        {
            const bf16* vb = lVt2 + (kt & 1) * VBUF;
            __builtin_amdgcn_s_setprio(1);
#pragma unroll
            for (int c2 = 0; c2 < 4; c2++) {
                bf16x8 bv0 = *(const bf16x8*)(vb + (size_t)lrow * VSTR2 + c2 * 32 + lch * 8);
                bf16x8 bv1 = *(const bf16x8*)(vb + (size_t)(16 + lrow) * VSTR2 + c2 * 32 + lch * 8);
#pragma unroll
                for (int t = 0; t < 2; t++) {
                    oacc[t][0] = __builtin_amdgcn_mfma_f32_16x16x32_bf16(apc[t][c2], bv0, oacc[t][0], 0, 0, 0);
                    oacc[t][1] = __builtin_amdgcn_mfma_f32_16x16x32_bf16(apc[t][c2], bv1, oacc[t][1], 0, 0, 0);
                }
            }
            __builtin_amdgcn_s_setprio(0);
        }

        if (kt < 3) __syncthreads();   // next tile staged + everyone done reading
    }

#pragma unroll
    for (int t = 0; t < 2; t++) {
#pragma unroll
        for (int r = 0; r < 4; r++) {
            const float lv  = __shfl(l_i[t], lch * 4 + r);
            const float inv = 1.f / fmaxf(lv, 1e-20f);
            const int n = qbase + t * 16 + lch * 4 + r;
            bf16* orow = Og + (size_t)(b * NTOK + n) * DIMC + h * HD;
            orow[lrow]      = (bf16)(oacc[t][0][r] * inv);
            orow[16 + lrow] = (bf16)(oacc[t][1][r] * inv);
        }
    }
}

// ---------------------------------------------------------------------------
extern "C" void kernel_launch(void* const* d_in, const int* in_sizes, int n_in,
                              void* d_out, int out_size, void* d_ws, size_t ws_size,
                              hipStream_t stream)
{
    if (ws_size < WS_SMALL) return;
    const bool BIG = (ws_size >= WS_BIG);

    const float* x      = (const float*)d_in[0];
    const float* maskp  = (const float*)d_in[4];
    const float* qkv_w  = (const float*)d_in[5];
    const float* qkv_b  = (const float*)d_in[6];
    const float* proj_w = (const float*)d_in[7];
    const float* proj_b = (const float*)d_in[8];

    char* ws = (char*)d_ws;
    size_t off = 0;
    bf16* wsWqT  = (bf16*)(ws + off); off += SZ_WQT;
    bf16* wsWpT  = (bf16*)(ws + off); off += SZ_WPT;
    bf16* wsPosT = (bf16*)(ws + off); off += SZ_POST;
    int*  wsFlag = (int*)(ws + off);  off += SZ_FLAG;
    bf16* wsB2 = nullptr;
    if (BIG) {
        wsB2 = (bf16*)(ws + off); off += SZ_B2;
        off += SZ_MT;              // legacy region, keeps proven layout
    } else {
        off = 1572864;
    }
    bf16* wsQ    = (bf16*)(ws + off); off += SZ_QKV;
    bf16* wsK    = (bf16*)(ws + off); off += SZ_QKV;
    bf16* wsV    = (bf16*)(ws + off); off += SZ_QKV;
    bf16* wsAttn = (bf16*)(ws + off);
    bf16* wsXb   = wsAttn;   // x-bf16 aliases attn-out: dead before attn writes

    hipMemsetAsync(wsFlag, 0, 4, stream);

    prep_kernel<<<NB_PREP, 256, 0, stream>>>(
        x, qkv_w, proj_w, maskp,
        (const float*)d_in[9],  (const float*)d_in[10], (const float*)d_in[11],
        (const float*)d_in[12], (const float*)d_in[13], (const float*)d_in[14],
        (const float*)d_in[15], (const float*)d_in[16], (const float*)d_in[17],
        (const float*)d_in[18], (const float*)d_in[19], (const float*)d_in[20],
        (const float*)d_in[21], (const float*)d_in[22],
        wsXb, wsWqT, wsWpT, wsFlag, wsPosT);

    if (BIG)
        bias2_build_kernel<<<(HEADS * NTOK * NTOK) / 256, 256, 0, stream>>>(wsPosT, wsB2);

    // QKV: [32768 x 384] @ [384 x 1152] -> scatter Q/K/V (Q pre-scaled)
    gemm_bt<0><<<dim3(256, 9), 256, 0, stream>>>(wsXb, wsWqT, qkv_b, wsQ, wsK, wsV,
                                                 nullptr, 384, 1152);

    // V pages -> V^T in place (768 x 32KB pages)
    vt_inplace_kernel<<<NWIN * HEADS, 256, 0, stream>>>(wsV);

    if (BIG)
        attn_kernel<1><<<NB_ATTN, 256, 0, stream>>>(
            wsQ, wsK, wsV, wsPosT, maskp, wsB2, wsFlag, wsAttn);
    else
        attn_kernel<0><<<NB_ATTN, 256, 0, stream>>>(
            wsQ, wsK, wsV, wsPosT, maskp, wsB2, wsFlag, wsAttn);

    // proj: [32768 x 384] @ [384 x 384] -> d_out (fp32)
    gemm_bt<1><<<dim3(256, 3), 256, 0, stream>>>(wsAttn, wsWpT, proj_b,
                                                 nullptr, nullptr, nullptr,
                                                 (float*)d_out, 384, 384);
}

// Round 11
// 428.834 us; speedup vs baseline: 1.0366x; 1.0366x over previous
//
#include <hip/hip_runtime.h>

// ---------------------------------------------------------------------------
// Attention_1752346656894: 3D-window attention w/ dynamic position bias.
// R17: revert attn to R10's proven 155us structure (R15/R16 showed achieved
// occupancy is pinned ~41% regardless of LDS cap -> per-kt dbuf + barriers
// only added cost). Bank the win elsewhere: gemm0 (MODE 0) now writes V
// DIRECTLY in V^T page layout (((b*H+h)*HD+dd)*NTOK+n — index-identical to
// what vt_inplace produced), deleting the vt_inplace kernel + launch gap.
// Cost: V-tile stores become ~4x transactions on V's 8.4MB (+3-8us in gemm0)
// vs saving ~16us kernel + ~10us launch.
// attn (== R10): full V^T staged to LDS via 8x global_load_lds width-16
// (VSTR=520), XCD-chunked swizzle, swapped QK^T, in-reg P repack (distinct-
// operand permlane), base-2 softmax, defer-max, one barrier total.
// ---------------------------------------------------------------------------

typedef __bf16 bf16;
typedef __bf16 bf16x4 __attribute__((ext_vector_type(4)));
typedef __bf16 bf16x8 __attribute__((ext_vector_type(8)));
typedef float  f32x4  __attribute__((ext_vector_type(4)));
typedef unsigned int u32;
typedef u32 u32x4v __attribute__((ext_vector_type(4)));

#define DIMC   384
#define HEADS  12
#define HD     32
#define NTOK   512
#define NWIN   64
#define LTAB   3375      // 15^3
#define LPAD   3392      // padded to 16B multiple (bf16)
#define PD     24
#define LOG2E  1.4426950408889634f
#define QPRE   (0.17677669529663687f * LOG2E)   // 32^-0.5 * log2(e)
#define VSTR   520       // lVt row stride (bf16): 512+8 -> 1040B, 16B-aligned

#define SZ_WQT  884736ll
#define SZ_WPT  294912ll
#define SZ_POST 81408ll        // bf16 [12][3392]
#define SZ_FLAG 256ll
#define SZ_B2   6291456ll      // bf16 [12][512][512]  ([h][q][k])
#define SZ_MT   4194304ll      // legacy region (unused, keeps layout)
#define SZ_QKV  25165824ll
#define WS_SMALL 102236160ull
#define WS_BIG   112410368ull

// prep kernel block ranges
#define NB_XC   12288   // 32768*384/4/256
#define NB_WQT  1728    // 384*1152/256
#define NB_WPT  576     // 384*384/256
#define NB_MSK  256
#define NB_POS  14      // ceil(3375/256)
#define NB_PREP (NB_XC + NB_WQT + NB_WPT + NB_MSK + NB_POS)

#define NB_ATTN (HEADS * NWIN * 4)   // 3072, divisible by 8

__device__ inline u32 cvtpk(float lo, float hi) {
    u32 r;
    asm("v_cvt_pk_bf16_f32 %0, %1, %2" : "=v"(r) : "v"(lo), "v"(hi));
    return r;
}
__device__ inline void plswap32(u32& a, u32& b) {
    asm("v_permlane32_swap_b32 %0, %1" : "+v"(a), "+v"(b));
}
__device__ inline void plswap16(u32& a, u32& b) {
    asm("v_permlane16_swap_b32 %0, %1" : "+v"(a), "+v"(b));
}
__device__ inline float ex2(float x) {
#if __has_builtin(__builtin_amdgcn_exp2f)
    return __builtin_amdgcn_exp2f(x);
#else
    float r; asm("v_exp_f32 %0, %1" : "=v"(r) : "v"(x)); return r;
#endif
}
__device__ inline void gload_lds16(const void* g, void* l) {
    __builtin_amdgcn_global_load_lds(
        (const __attribute__((address_space(1))) void*)g,
        (__attribute__((address_space(3))) void*)l, 16, 0, 0);
}

// ---------------------------------------------------------------------------
__device__ inline void ln_relu24(const float* x, const float* __restrict__ g,
                                 const float* __restrict__ b, float* y)
{
    float mean = 0.f;
#pragma unroll
    for (int j = 0; j < PD; j++) mean += x[j];
    mean *= (1.f / PD);
    float var = 0.f;
#pragma unroll
    for (int j = 0; j < PD; j++) { float d = x[j] - mean; var += d * d; }
    var *= (1.f / PD);
    float inv = rsqrtf(var + 1e-5f);
#pragma unroll
    for (int j = 0; j < PD; j++) {
        float t = (x[j] - mean) * inv * g[j] + b[j];
        y[j] = t > 0.f ? t : 0.f;
    }
}

// ---------------------------------------------------------------------------
// Fused preprocessing: [xcast | qkv_w^T | proj_w^T | mask_detect | pos_mlp]
__global__ __launch_bounds__(256) void prep_kernel(
    const float* __restrict__ x,
    const float* __restrict__ qkv_w, const float* __restrict__ proj_w,
    const float* __restrict__ mask,
    const float* __restrict__ pw,  const float* __restrict__ pb,
    const float* __restrict__ g1,  const float* __restrict__ b1,
    const float* __restrict__ w1,  const float* __restrict__ bb1,
    const float* __restrict__ g2,  const float* __restrict__ b2,
    const float* __restrict__ w2,  const float* __restrict__ bb2,
    const float* __restrict__ g3,  const float* __restrict__ b3,
    const float* __restrict__ w3,  const float* __restrict__ bb3,
    bf16* __restrict__ xb, bf16* __restrict__ wqT, bf16* __restrict__ wpT,
    int* __restrict__ flag, bf16* __restrict__ posTg)
{
    const int tid = threadIdx.x;
    int bx = blockIdx.x;

    if (bx < NB_XC) {                       // x fp32 -> bf16
        const int i = bx * 256 + tid;
        const f32x4 v = *(const f32x4*)(x + (size_t)i * 4);
        bf16x4 o;
#pragma unroll
        for (int j = 0; j < 4; j++) o[j] = (bf16)v[j];
        *(bf16x4*)(xb + (size_t)i * 4) = o;
        return;
    }
    bx -= NB_XC;
    if (bx < NB_WQT) {                      // qkv_w [384][1152] -> [1152][384] bf16
        const int idx = bx * 256 + tid;
        const int n = idx / 384, k = idx - n * 384;
        wqT[idx] = (bf16)qkv_w[(size_t)k * 1152 + n];
        return;
    }
    bx -= NB_WQT;
    if (bx < NB_WPT) {                      // proj_w [384][384] -> transposed bf16
        const int idx = bx * 256 + tid;
        const int n = idx / 384, k = idx - n * 384;
        wpT[idx] = (bf16)proj_w[(size_t)k * 384 + n];
        return;
    }
    bx -= NB_WPT;
    if (bx < NB_MSK) {                      // mask nonzero detect
        const int i = bx * 256 + tid;
        const float* p = mask + (size_t)i * 32;
        float s = 0.f;
#pragma unroll
        for (int j = 0; j < 32; j++) s += fabsf(p[j]);
        if (!(s == 0.f)) atomicOr(flag, 1);
        return;
    }
    bx -= NB_MSK;
    {                                       // pos MLP (output *LOG2E)
        const int l = bx * 256 + tid;
        if (l >= LTAB) return;
        const int ih = l / 225, iw = (l / 15) % 15, id = l % 15;
        const float c0 = (float)(ih - 7), c1 = (float)(iw - 7), c2 = (float)(id - 7);
        float xx[PD], y[PD];
#pragma unroll
        for (int j = 0; j < PD; j++)
            xx[j] = c0 * pw[j] + c1 * pw[PD + j] + c2 * pw[2 * PD + j] + pb[j];
        ln_relu24(xx, g1, b1, y);
#pragma unroll
        for (int j = 0; j < PD; j++) {
            float a = bb1[j];
#pragma unroll
            for (int i = 0; i < PD; i++) a += y[i] * w1[i * PD + j];
            xx[j] = a;
        }
        ln_relu24(xx, g2, b2, y);
#pragma unroll
        for (int j = 0; j < PD; j++) {
            float a = bb2[j];
#pragma unroll
            for (int i = 0; i < PD; i++) a += y[i] * w2[i * PD + j];
            xx[j] = a;
        }
        ln_relu24(xx, g3, b3, y);
#pragma unroll
        for (int hh = 0; hh < HEADS; hh++) {
            float a = bb3[hh];
#pragma unroll
            for (int i = 0; i < PD; i++) a += y[i] * w3[i * HEADS + hh];
            posTg[hh * LPAD + l] = (bf16)(a * LOG2E);
        }
    }
}

// ---------------------------------------------------------------------------
// bias2[h][q][k] = pos-bias (already *LOG2E). Coalesced writes along k.
__global__ __launch_bounds__(256) void bias2_build_kernel(
    const bf16* __restrict__ posTg, bf16* __restrict__ bias2)
{
    int idx = blockIdx.x * 256 + threadIdx.x;   // 12*512*512 exact grid
    int h = idx >> 18;
    int q = (idx >> 9) & 511;
    int m = idx & 511;
    int dh = (q >> 6) - (m >> 6) + 7;
    int dw = ((q >> 3) & 7) - ((m >> 3) & 7) + 7;
    int dd = (q & 7) - (m & 7) + 7;
    bias2[idx] = posTg[h * LPAD + dh * 225 + dw * 15 + dd];
}

// ---------------------------------------------------------------------------
// GEMM: C[M][N] = A[M][K] @ Bt[N][K]^T + bias. 128x128 tile, BK=64.
// MODE 0: scatter bf16 into Q/K/V; Q prescaled by QPRE; V written in
//         TRANSPOSED page layout [page][32][512] (replaces vt_inplace).
// MODE 1: write fp32 row-major to Of.
template <int MODE>
__global__ __launch_bounds__(256) void gemm_bt(
    const bf16* __restrict__ A, const bf16* __restrict__ Bt,
    const float* __restrict__ bias,
    bf16* __restrict__ O0, bf16* __restrict__ O1, bf16* __restrict__ O2,
    float* __restrict__ Of, int K, int N)
{
    __shared__ __align__(16) bf16 lA[128 * 64];
    __shared__ __align__(16) bf16 lB[128 * 64];
    const int row0 = blockIdx.x * 128;
    const int col0 = blockIdx.y * 128;
    const int tid  = threadIdx.x;
    const int lane = tid & 63;
    const int wave = tid >> 6;
    const int r0   = (wave >> 1) * 64;
    const int c0   = (wave & 1) * 64;
    const int lrow = lane & 15;
    const int lch  = lane >> 4;

    f32x4 acc[4][4];
    const f32x4 zero4 = {0.f, 0.f, 0.f, 0.f};
#pragma unroll
    for (int i = 0; i < 4; i++)
#pragma unroll
        for (int j = 0; j < 4; j++) acc[i][j] = zero4;

    for (int kt = 0; kt < K; kt += 64) {
        __syncthreads();
#pragma unroll
        for (int it = 0; it < 4; it++) {
            const int c  = tid + it * 256;
            const int rr = c >> 3;
            const int cc = (c & 7) * 8;
            bf16* la = lA + (size_t)(it * 256 + wave * 64) * 8;
            bf16* lb = lB + (size_t)(it * 256 + wave * 64) * 8;
            gload_lds16(A  + (size_t)(row0 + rr) * K + kt + cc, la);
            gload_lds16(Bt + (size_t)(col0 + rr) * K + kt + cc, lb);
        }
        __syncthreads();
#pragma unroll
        for (int kk = 0; kk < 64; kk += 32) {
            bf16x8 af[4], bfr[4];
#pragma unroll
            for (int i = 0; i < 4; i++)
                af[i] = *(const bf16x8*)(lA + (r0 + i * 16 + lrow) * 64 + kk + lch * 8);
#pragma unroll
            for (int j = 0; j < 4; j++)
                bfr[j] = *(const bf16x8*)(lB + (c0 + j * 16 + lrow) * 64 + kk + lch * 8);
#pragma unroll
            for (int i = 0; i < 4; i++)
#pragma unroll
                for (int j = 0; j < 4; j++)
                    acc[i][j] = __builtin_amdgcn_mfma_f32_16x16x32_bf16(af[i], bfr[j], acc[i][j], 0, 0, 0);
        }
    }

#pragma unroll
    for (int i = 0; i < 4; i++) {
#pragma unroll
        for (int j = 0; j < 4; j++) {
#pragma unroll
            for (int r = 0; r < 4; r++) {
                const int mrow = row0 + r0 + i * 16 + lch * 4 + r;
                const int ncol = col0 + c0 + j * 16 + lrow;
                const float v = acc[i][j][r] + bias[ncol];
                if (MODE == 0) {
                    const int t    = ncol >= 768 ? 2 : (ncol >= 384 ? 1 : 0);
                    const int rem2 = ncol - t * 384;
                    const int hh   = rem2 >> 5;
                    const int dd   = rem2 & 31;
                    const int bwin = mrow >> 9;
                    const int n    = mrow & 511;
                    const int page = bwin * HEADS + hh;
                    if (t == 2) {
                        // V in transposed page layout [page][32][512]
                        O2[((size_t)page * HD + dd) * NTOK + n] = (bf16)v;
                    } else {
                        bf16* dst = (t == 0) ? O0 : O1;
                        const float vv = (t == 0) ? v * QPRE : v;   // Q prescale
                        dst[((size_t)page * NTOK + n) * HD + dd] = (bf16)vv;
                    }
                } else {
                    Of[(size_t)mrow * N + ncol] = v;
                }
            }
        }
    }
}

// ---------------------------------------------------------------------------
// Flash attention (== R10): swapped QK^T, P repack in regs, XCD-chunked
// swizzle. V^T staged global->LDS via global_load_lds (linear rows); PV
// reads LDS at VSTR=520. T13 defer-max. One barrier total.
template <int BIG>
__global__ __launch_bounds__(256, 4) void attn_kernel(
    const bf16* __restrict__ Qg, const bf16* __restrict__ Kg,
    const bf16* __restrict__ Vtg, const bf16* __restrict__ posTg,
    const float* __restrict__ maskg, const bf16* __restrict__ bias2,
    const int* __restrict__ mflag, bf16* __restrict__ Og)
{
    __shared__ __align__(16) bf16 lVt[32 * VSTR];          // 33,280 B
    __shared__ __align__(16) bf16 lPos[BIG ? 16 : LPAD];

    // XCD-chunked swizzle (bijective: 3072 % 8 == 0)
    const int idx = (blockIdx.x & 7) * (NB_ATTN / 8) + (blockIdx.x >> 3);
    const int h   = idx >> 8;
    const int rem = idx & 255;
    const int b   = rem >> 2;
    const int qt  = rem & 3;
    const int g   = b & 7;
    const int tid = threadIdx.x;
    const int lane = tid & 63;
    const int wave = tid >> 6;
    const int lrow = lane & 15;
    const int lch  = lane >> 4;
    const int msk  = *mflag;

    const bf16* Qp  = Qg  + (size_t)(b * HEADS + h) * NTOK * HD;
    const bf16* Kp  = Kg  + (size_t)(b * HEADS + h) * NTOK * HD;
    const bf16* Vtp = Vtg + (size_t)(b * HEADS + h) * NTOK * HD;   // [32][512]
    const float* Mp = maskg + (size_t)g * NTOK * NTOK;
    const bf16* B2p = bias2 + (size_t)h * NTOK * NTOK;             // [q][k]

    // stage V^T rows into LDS: 8 global_load_lds per wave, one 1024B row each
    {
        const int d0 = wave * 8;
#pragma unroll
        for (int rr = 0; rr < 8; rr++) {
            const int d = d0 + rr;
            gload_lds16(Vtp + (size_t)d * NTOK + lane * 8, lVt + (size_t)d * VSTR);
        }
    }
    if (!BIG) {
        const uint4* src = (const uint4*)(posTg + h * LPAD);
        for (int i = tid; i < LPAD * 2 / 16; i += 256)
            ((uint4*)lPos)[i] = src[i];
    }
    __syncthreads();   // vmcnt(0) drain -> gload_lds complete

    const int qbase = qt * 128 + wave * 32;

    bf16x8 qf[2];
#pragma unroll
    for (int t = 0; t < 2; t++)
        qf[t] = *(const bf16x8*)(Qp + (size_t)(qbase + t * 16 + lrow) * HD + lch * 8);

    int qc0[2] = {0, 0}, qc1[2] = {0, 0}, qc2[2] = {0, 0};
    if (!BIG) {
#pragma unroll
        for (int t = 0; t < 2; t++) {
            const int q = qbase + t * 16 + lrow;
            qc0[t] = q >> 6; qc1[t] = (q >> 3) & 7; qc2[t] = q & 7;
        }
    }

    float m_i[2] = {-1e30f, -1e30f};
    float l_i[2] = {0.f, 0.f};
    f32x4 oacc[2][2];
    const f32x4 zero4 = {0.f, 0.f, 0.f, 0.f};
    oacc[0][0] = zero4; oacc[0][1] = zero4;
    oacc[1][0] = zero4; oacc[1][1] = zero4;

    for (int kt = 0; kt < 4; kt++) {
        bf16x8 apc[2][4];   // packed P, A-fragment layout, per q-tile per 32-k chunk
        float alr[2];
        bool doresc[2];

#pragma unroll
        for (int t = 0; t < 2; t++) {
            const int qrow = qbase + t * 16 + lrow;
            f32x4 sf[8];

            // bias prefetch (BIG): 8 x bf16x4, vectorized along k
            bf16x4 bld[8];
            if (BIG) {
                const bf16* brow = B2p + (size_t)qrow * NTOK + kt * 128 + lch * 4;
#pragma unroll
                for (int ct = 0; ct < 8; ct++)
                    bld[ct] = *(const bf16x4*)(brow + ct * 16);
            }

            // S^T = K @ Q^T  (C layout: row = k-token, col = q = lrow)
#pragma unroll
            for (int ct = 0; ct < 8; ct++) {
                bf16x8 kf = *(const bf16x8*)(Kp + (size_t)(kt * 128 + ct * 16 + lrow) * HD + lch * 8);
                sf[ct] = __builtin_amdgcn_mfma_f32_16x16x32_bf16(kf, qf[t], zero4, 0, 0, 0);
            }

            if (BIG) {
#pragma unroll
                for (int ct = 0; ct < 8; ct++)
#pragma unroll
                    for (int r = 0; r < 4; r++)
                        sf[ct][r] += (float)bld[ct][r];
            } else {
#pragma unroll
                for (int ct = 0; ct < 8; ct++) {
#pragma unroll
                    for (int r = 0; r < 4; r++) {
                        const int k = kt * 128 + ct * 16 + lch * 4 + r;
                        const int rpi = (qc0[t] - (k >> 6) + 7) * 225
                                      + (qc1[t] - ((k >> 3) & 7) + 7) * 15
                                      + (qc2[t] - (k & 7) + 7);
                        sf[ct][r] += (float)lPos[rpi];
                    }
                }
            }
            if (msk) {
                const float* mrow = Mp + (size_t)qrow * NTOK + kt * 128 + lch * 4;
#pragma unroll
                for (int ct = 0; ct < 8; ct++) {
                    f32x4 mv = *(const f32x4*)(mrow + ct * 16);
#pragma unroll
                    for (int r = 0; r < 4; r++)
                        sf[ct][r] = fmaf(mv[r], LOG2E, sf[ct][r]);
                }
            }

            // online softmax (base 2): in-lane tree + 2 cross-lane hops
            float px[8];
#pragma unroll
            for (int ct = 0; ct < 8; ct++)
                px[ct] = fmaxf(fmaxf(sf[ct][0], sf[ct][1]), fmaxf(sf[ct][2], sf[ct][3]));
            float mx = fmaxf(fmaxf(fmaxf(px[0], px[1]), fmaxf(px[2], px[3])),
                             fmaxf(fmaxf(px[4], px[5]), fmaxf(px[6], px[7])));
            mx = fmaxf(mx, __shfl_xor(mx, 16));
            mx = fmaxf(mx, __shfl_xor(mx, 32));

            // T13 defer-max: keep stale m while growth <= 8 (p <= 2^8, bf16-ok)
            if (__all(mx <= m_i[t] + 8.f)) {
                alr[t] = 1.f;
                doresc[t] = false;
            } else {
                const float mnew = fmaxf(m_i[t], mx);
                alr[t] = ex2(m_i[t] - mnew);
                m_i[t] = mnew;
                doresc[t] = true;
            }

            float s0 = 0.f, s1 = 0.f;
#pragma unroll
            for (int ct = 0; ct < 8; ct++) {
#pragma unroll
                for (int r = 0; r < 4; r++)
                    sf[ct][r] = ex2(sf[ct][r] - m_i[t]);
                s0 += sf[ct][0] + sf[ct][1];
                s1 += sf[ct][2] + sf[ct][3];
            }
            float ls = s0 + s1;
            ls += __shfl_xor(ls, 16);
            ls += __shfl_xor(ls, 32);
            l_i[t] = l_i[t] * alr[t] + ls;

            // pack P -> A-fragments, fully in registers (cvt_pk + permlane;
            // distinct operands — proven since R7).
#pragma unroll
            for (int c2 = 0; c2 < 4; c2++) {
                u32 a01 = cvtpk(sf[2 * c2][0],     sf[2 * c2][1]);
                u32 a23 = cvtpk(sf[2 * c2][2],     sf[2 * c2][3]);
                u32 b01 = cvtpk(sf[2 * c2 + 1][0], sf[2 * c2 + 1][1]);
                u32 b23 = cvtpk(sf[2 * c2 + 1][2], sf[2 * c2 + 1][3]);
                plswap32(a01, b01); plswap16(a01, b01);
                plswap32(a23, b23); plswap16(a23, b23);
                u32x4v w; w[0] = a01; w[1] = a23; w[2] = b01; w[3] = b23;
                apc[t][c2] = __builtin_bit_cast(bf16x8, w);
            }
        }

        // rescale O by alpha (wave-uniform skip when deferred)
#pragma unroll
        for (int t = 0; t < 2; t++) {
            if (doresc[t]) {
#pragma unroll
                for (int r = 0; r < 4; r++) {
                    const float a = __shfl(alr[t], lch * 4 + r);
                    oacc[t][0][r] *= a;
                    oacc[t][1][r] *= a;
                }
            }
        }

        // P @ V from LDS V^T
#pragma unroll
        for (int c2 = 0; c2 < 4; c2++) {
            const int mofs = kt * 128 + c2 * 32;
            bf16x8 bv0 = *(const bf16x8*)(lVt + (size_t)lrow * VSTR + mofs + lch * 8);
            bf16x8 bv1 = *(const bf16x8*)(lVt + (size_t)(16 + lrow) * VSTR + mofs + lch * 8);
#pragma unroll
            for (int t = 0; t < 2; t++) {
                oacc[t][0] = __builtin_amdgcn_mfma_f32_16x16x32_bf16(apc[t][c2], bv0, oacc[t][0], 0, 0, 0);
                oacc[t][1] = __builtin_amdgcn_mfma_f32_16x16x32_bf16(apc[t][c2], bv1, oacc[t][1], 0, 0, 0);
            }
        }
    }

#pragma unroll
    for (int t = 0; t < 2; t++) {
#pragma unroll
        for (int r = 0; r < 4; r++) {
            const float lv  = __shfl(l_i[t], lch * 4 + r);
            const float inv = 1.f / fmaxf(lv, 1e-20f);
            const int n = qbase + t * 16 + lch * 4 + r;
            bf16* orow = Og + (size_t)(b * NTOK + n) * DIMC + h * HD;
            orow[lrow]      = (bf16)(oacc[t][0][r] * inv);
            orow[16 + lrow] = (bf16)(oacc[t][1][r] * inv);
        }
    }
}

// ---------------------------------------------------------------------------
extern "C" void kernel_launch(void* const* d_in, const int* in_sizes, int n_in,
                              void* d_out, int out_size, void* d_ws, size_t ws_size,
                              hipStream_t stream)
{
    if (ws_size < WS_SMALL) return;
    const bool BIG = (ws_size >= WS_BIG);

    const float* x      = (const float*)d_in[0];
    const float* maskp  = (const float*)d_in[4];
    const float* qkv_w  = (const float*)d_in[5];
    const float* qkv_b  = (const float*)d_in[6];
    const float* proj_w = (const float*)d_in[7];
    const float* proj_b = (const float*)d_in[8];

    char* ws = (char*)d_ws;
    size_t off = 0;
    bf16* wsWqT  = (bf16*)(ws + off); off += SZ_WQT;
    bf16* wsWpT  = (bf16*)(ws + off); off += SZ_WPT;
    bf16* wsPosT = (bf16*)(ws + off); off += SZ_POST;
    int*  wsFlag = (int*)(ws + off);  off += SZ_FLAG;
    bf16* wsB2 = nullptr;
    if (BIG) {
        wsB2 = (bf16*)(ws + off); off += SZ_B2;
        off += SZ_MT;              // legacy region, keeps proven layout
    } else {
        off = 1572864;
    }
    bf16* wsQ    = (bf16*)(ws + off); off += SZ_QKV;
    bf16* wsK    = (bf16*)(ws + off); off += SZ_QKV;
    bf16* wsV    = (bf16*)(ws + off); off += SZ_QKV;
    bf16* wsAttn = (bf16*)(ws + off);
    bf16* wsXb   = wsAttn;   // x-bf16 aliases attn-out: dead before attn writes

    hipMemsetAsync(wsFlag, 0, 4, stream);

    prep_kernel<<<NB_PREP, 256, 0, stream>>>(
        x, qkv_w, proj_w, maskp,
        (const float*)d_in[9],  (const float*)d_in[10], (const float*)d_in[11],
        (const float*)d_in[12], (const float*)d_in[13], (const float*)d_in[14],
        (const float*)d_in[15], (const float*)d_in[16], (const float*)d_in[17],
        (const float*)d_in[18], (const float*)d_in[19], (const float*)d_in[20],
        (const float*)d_in[21], (const float*)d_in[22],
        wsXb, wsWqT, wsWpT, wsFlag, wsPosT);

    if (BIG)
        bias2_build_kernel<<<(HEADS * NTOK * NTOK) / 256, 256, 0, stream>>>(wsPosT, wsB2);

    // QKV: [32768 x 384] @ [384 x 1152] -> scatter Q/K/V
    // (Q pre-scaled; V written directly in V^T page layout)
    gemm_bt<0><<<dim3(256, 9), 256, 0, stream>>>(wsXb, wsWqT, qkv_b, wsQ, wsK, wsV,
                                                 nullptr, 384, 1152);

    if (BIG)
        attn_kernel<1><<<NB_ATTN, 256, 0, stream>>>(
            wsQ, wsK, wsV, wsPosT, maskp, wsB2, wsFlag, wsAttn);
    else
        attn_kernel<0><<<NB_ATTN, 256, 0, stream>>>(
            wsQ, wsK, wsV, wsPosT, maskp, wsB2, wsFlag, wsAttn);

    // proj: [32768 x 384] @ [384 x 384] -> d_out (fp32)
    gemm_bt<1><<<dim3(256, 3), 256, 0, stream>>>(wsAttn, wsWpT, proj_b,
                                                 nullptr, nullptr, nullptr,
                                                 (float*)d_out, 384, 384);
}

// Round 12
// 405.173 us; speedup vs baseline: 1.0972x; 1.0584x over previous
//
#include <hip/hip_runtime.h>

// ---------------------------------------------------------------------------
// Attention_1752346656894: 3D-window attention w/ dynamic position bias.
// R18: restore R10's proven best config (attn 155us, vt_inplace, normal V
// layout — R17's V^T-direct-write cost +11us in scattered epilogue stores).
// New: GEMM tiles 128x128 -> 256x128 with 512 threads (8 waves x 64x64).
// Rationale: gemm0 is K-short (384 = 6 BK-steps); each K-step pays 2 full
// barrier+vmcnt drains that short-K can't amortize. 2x FLOPs per barrier
// halves that cost; blocks 2304->1152 / 768->384 halve ramp overhead.
// LDS 48KB -> 3 blocks/CU x 8 waves = 24 waves/CU (>= current 20).
// attn (== R10): full V^T staged to LDS via 8x global_load_lds width-16
// (VSTR=520), XCD-chunked swizzle, swapped QK^T, in-reg P repack, base-2
// softmax, defer-max, one barrier total.
// ---------------------------------------------------------------------------

typedef __bf16 bf16;
typedef __bf16 bf16x4 __attribute__((ext_vector_type(4)));
typedef __bf16 bf16x8 __attribute__((ext_vector_type(8)));
typedef float  f32x4  __attribute__((ext_vector_type(4)));
typedef unsigned int u32;
typedef u32 u32x4v __attribute__((ext_vector_type(4)));

#define DIMC   384
#define HEADS  12
#define HD     32
#define NTOK   512
#define NWIN   64
#define LTAB   3375      // 15^3
#define LPAD   3392      // padded to 16B multiple (bf16)
#define PD     24
#define LOG2E  1.4426950408889634f
#define QPRE   (0.17677669529663687f * LOG2E)   // 32^-0.5 * log2(e)
#define VSTR   520       // lVt row stride (bf16): 512+8 -> 1040B, 16B-aligned

#define SZ_WQT  884736ll
#define SZ_WPT  294912ll
#define SZ_POST 81408ll        // bf16 [12][3392]
#define SZ_FLAG 256ll
#define SZ_B2   6291456ll      // bf16 [12][512][512]  ([h][q][k])
#define SZ_MT   4194304ll      // legacy region (unused, keeps layout)
#define SZ_QKV  25165824ll
#define WS_SMALL 102236160ull
#define WS_BIG   112410368ull

// prep kernel block ranges
#define NB_XC   12288   // 32768*384/4/256
#define NB_WQT  1728    // 384*1152/256
#define NB_WPT  576     // 384*384/256
#define NB_MSK  256
#define NB_POS  14      // ceil(3375/256)
#define NB_PREP (NB_XC + NB_WQT + NB_WPT + NB_MSK + NB_POS)

#define NB_ATTN (HEADS * NWIN * 4)   // 3072, divisible by 8

__device__ inline u32 cvtpk(float lo, float hi) {
    u32 r;
    asm("v_cvt_pk_bf16_f32 %0, %1, %2" : "=v"(r) : "v"(lo), "v"(hi));
    return r;
}
__device__ inline void plswap32(u32& a, u32& b) {
    asm("v_permlane32_swap_b32 %0, %1" : "+v"(a), "+v"(b));
}
__device__ inline void plswap16(u32& a, u32& b) {
    asm("v_permlane16_swap_b32 %0, %1" : "+v"(a), "+v"(b));
}
__device__ inline float ex2(float x) {
#if __has_builtin(__builtin_amdgcn_exp2f)
    return __builtin_amdgcn_exp2f(x);
#else
    float r; asm("v_exp_f32 %0, %1" : "=v"(r) : "v"(x)); return r;
#endif
}
__device__ inline void gload_lds16(const void* g, void* l) {
    __builtin_amdgcn_global_load_lds(
        (const __attribute__((address_space(1))) void*)g,
        (__attribute__((address_space(3))) void*)l, 16, 0, 0);
}

// ---------------------------------------------------------------------------
__device__ inline void ln_relu24(const float* x, const float* __restrict__ g,
                                 const float* __restrict__ b, float* y)
{
    float mean = 0.f;
#pragma unroll
    for (int j = 0; j < PD; j++) mean += x[j];
    mean *= (1.f / PD);
    float var = 0.f;
#pragma unroll
    for (int j = 0; j < PD; j++) { float d = x[j] - mean; var += d * d; }
    var *= (1.f / PD);
    float inv = rsqrtf(var + 1e-5f);
#pragma unroll
    for (int j = 0; j < PD; j++) {
        float t = (x[j] - mean) * inv * g[j] + b[j];
        y[j] = t > 0.f ? t : 0.f;
    }
}

// ---------------------------------------------------------------------------
// Fused preprocessing: [xcast | qkv_w^T | proj_w^T | mask_detect | pos_mlp]
__global__ __launch_bounds__(256) void prep_kernel(
    const float* __restrict__ x,
    const float* __restrict__ qkv_w, const float* __restrict__ proj_w,
    const float* __restrict__ mask,
    const float* __restrict__ pw,  const float* __restrict__ pb,
    const float* __restrict__ g1,  const float* __restrict__ b1,
    const float* __restrict__ w1,  const float* __restrict__ bb1,
    const float* __restrict__ g2,  const float* __restrict__ b2,
    const float* __restrict__ w2,  const float* __restrict__ bb2,
    const float* __restrict__ g3,  const float* __restrict__ b3,
    const float* __restrict__ w3,  const float* __restrict__ bb3,
    bf16* __restrict__ xb, bf16* __restrict__ wqT, bf16* __restrict__ wpT,
    int* __restrict__ flag, bf16* __restrict__ posTg)
{
    const int tid = threadIdx.x;
    int bx = blockIdx.x;

    if (bx < NB_XC) {                       // x fp32 -> bf16
        const int i = bx * 256 + tid;
        const f32x4 v = *(const f32x4*)(x + (size_t)i * 4);
        bf16x4 o;
#pragma unroll
        for (int j = 0; j < 4; j++) o[j] = (bf16)v[j];
        *(bf16x4*)(xb + (size_t)i * 4) = o;
        return;
    }
    bx -= NB_XC;
    if (bx < NB_WQT) {                      // qkv_w [384][1152] -> [1152][384] bf16
        const int idx = bx * 256 + tid;
        const int n = idx / 384, k = idx - n * 384;
        wqT[idx] = (bf16)qkv_w[(size_t)k * 1152 + n];
        return;
    }
    bx -= NB_WQT;
    if (bx < NB_WPT) {                      // proj_w [384][384] -> transposed bf16
        const int idx = bx * 256 + tid;
        const int n = idx / 384, k = idx - n * 384;
        wpT[idx] = (bf16)proj_w[(size_t)k * 384 + n];
        return;
    }
    bx -= NB_WPT;
    if (bx < NB_MSK) {                      // mask nonzero detect
        const int i = bx * 256 + tid;
        const float* p = mask + (size_t)i * 32;
        float s = 0.f;
#pragma unroll
        for (int j = 0; j < 32; j++) s += fabsf(p[j]);
        if (!(s == 0.f)) atomicOr(flag, 1);
        return;
    }
    bx -= NB_MSK;
    {                                       // pos MLP (output *LOG2E)
        const int l = bx * 256 + tid;
        if (l >= LTAB) return;
        const int ih = l / 225, iw = (l / 15) % 15, id = l % 15;
        const float c0 = (float)(ih - 7), c1 = (float)(iw - 7), c2 = (float)(id - 7);
        float xx[PD], y[PD];
#pragma unroll
        for (int j = 0; j < PD; j++)
            xx[j] = c0 * pw[j] + c1 * pw[PD + j] + c2 * pw[2 * PD + j] + pb[j];
        ln_relu24(xx, g1, b1, y);
#pragma unroll
        for (int j = 0; j < PD; j++) {
            float a = bb1[j];
#pragma unroll
            for (int i = 0; i < PD; i++) a += y[i] * w1[i * PD + j];
            xx[j] = a;
        }
        ln_relu24(xx, g2, b2, y);
#pragma unroll
        for (int j = 0; j < PD; j++) {
            float a = bb2[j];
#pragma unroll
            for (int i = 0; i < PD; i++) a += y[i] * w2[i * PD + j];
            xx[j] = a;
        }
        ln_relu24(xx, g3, b3, y);
#pragma unroll
        for (int hh = 0; hh < HEADS; hh++) {
            float a = bb3[hh];
#pragma unroll
            for (int i = 0; i < PD; i++) a += y[i] * w3[i * HEADS + hh];
            posTg[hh * LPAD + l] = (bf16)(a * LOG2E);
        }
    }
}

// ---------------------------------------------------------------------------
// bias2[h][q][k] = pos-bias (already *LOG2E). Coalesced writes along k.
__global__ __launch_bounds__(256) void bias2_build_kernel(
    const bf16* __restrict__ posTg, bf16* __restrict__ bias2)
{
    int idx = blockIdx.x * 256 + threadIdx.x;   // 12*512*512 exact grid
    int h = idx >> 18;
    int q = (idx >> 9) & 511;
    int m = idx & 511;
    int dh = (q >> 6) - (m >> 6) + 7;
    int dw = ((q >> 3) & 7) - ((m >> 3) & 7) + 7;
    int dd = (q & 7) - (m & 7) + 7;
    bias2[idx] = posTg[h * LPAD + dh * 225 + dw * 15 + dd];
}

// ---------------------------------------------------------------------------
// In-place per-(b,h) page transpose: V[page][512][32] -> V^T[page][32][512].
__global__ __launch_bounds__(256) void vt_inplace_kernel(bf16* __restrict__ V)
{
    __shared__ __align__(16) bf16 tile[32 * 520];
    bf16* base = V + (size_t)blockIdx.x * (NTOK * HD);
    const int tid = threadIdx.x;
    const int nq = tid >> 2;            // 0..63
    const int c4 = tid & 3;
    const int d0 = c4 * 8;
#pragma unroll
    for (int it = 0; it < 8; it++) {
        const int n = nq + it * 64;
        bf16x8 v = *(const bf16x8*)(base + n * HD + d0);
#pragma unroll
        for (int j = 0; j < 8; j++) {   // staggered to break d0-group conflicts
            const int jj = (j + (c4 << 1)) & 7;
            tile[(d0 + jj) * 520 + n] = v[jj];
        }
    }
    __syncthreads();
#pragma unroll
    for (int it = 0; it < 8; it++) {
        const int o = it * 2048 + tid * 8;
        const int d = o >> 9, n = o & 511;
        bf16x8 w = *(const bf16x8*)(tile + d * 520 + n);
        *(bf16x8*)(base + d * NTOK + n) = w;
    }
}

// ---------------------------------------------------------------------------
// GEMM: C[M][N] = A[M][K] @ Bt[N][K]^T + bias. 256x128 tile, BK=64,
// 512 threads (8 waves, 64x64 each). Short-K friendly: 2x FLOPs per
// barrier-drain vs 128x128.
// MODE 0: scatter bf16 into Q/K/V; Q prescaled by QPRE.
// MODE 1: write fp32 row-major to Of.
template <int MODE>
__global__ __launch_bounds__(512) void gemm_bt(
    const bf16* __restrict__ A, const bf16* __restrict__ Bt,
    const float* __restrict__ bias,
    bf16* __restrict__ O0, bf16* __restrict__ O1, bf16* __restrict__ O2,
    float* __restrict__ Of, int K, int N)
{
    __shared__ __align__(16) bf16 lA[256 * 64];   // 32 KB
    __shared__ __align__(16) bf16 lB[128 * 64];   // 16 KB
    const int row0 = blockIdx.x * 256;
    const int col0 = blockIdx.y * 128;
    const int tid  = threadIdx.x;
    const int lane = tid & 63;
    const int wave = tid >> 6;           // 0..7
    const int r0   = (wave >> 1) * 64;   // 0,64,128,192
    const int c0   = (wave & 1) * 64;    // 0,64
    const int lrow = lane & 15;
    const int lch  = lane >> 4;

    f32x4 acc[4][4];
    const f32x4 zero4 = {0.f, 0.f, 0.f, 0.f};
#pragma unroll
    for (int i = 0; i < 4; i++)
#pragma unroll
        for (int j = 0; j < 4; j++) acc[i][j] = zero4;

    for (int kt = 0; kt < K; kt += 64) {
        __syncthreads();
        // A tile: 256x64 = 2048 16B-chunks; 512 thr -> 4 each
#pragma unroll
        for (int it = 0; it < 4; it++) {
            const int c  = tid + it * 512;
            const int rr = c >> 3;
            const int cc = (c & 7) * 8;
            bf16* la = lA + (size_t)(it * 512 + wave * 64) * 8;
            gload_lds16(A + (size_t)(row0 + rr) * K + kt + cc, la);
        }
        // B tile: 128x64 = 1024 chunks; 2 each
#pragma unroll
        for (int it = 0; it < 2; it++) {
            const int c  = tid + it * 512;
            const int rr = c >> 3;
            const int cc = (c & 7) * 8;
            bf16* lb = lB + (size_t)(it * 512 + wave * 64) * 8;
            gload_lds16(Bt + (size_t)(col0 + rr) * K + kt + cc, lb);
        }
        __syncthreads();
#pragma unroll
        for (int kk = 0; kk < 64; kk += 32) {
            bf16x8 af[4], bfr[4];
#pragma unroll
            for (int i = 0; i < 4; i++)
                af[i] = *(const bf16x8*)(lA + (r0 + i * 16 + lrow) * 64 + kk + lch * 8);
#pragma unroll
            for (int j = 0; j < 4; j++)
                bfr[j] = *(const bf16x8*)(lB + (c0 + j * 16 + lrow) * 64 + kk + lch * 8);
#pragma unroll
            for (int i = 0; i < 4; i++)
#pragma unroll
                for (int j = 0; j < 4; j++)
                    acc[i][j] = __builtin_amdgcn_mfma_f32_16x16x32_bf16(af[i], bfr[j], acc[i][j], 0, 0, 0);
        }
    }

#pragma unroll
    for (int i = 0; i < 4; i++) {
#pragma unroll
        for (int j = 0; j < 4; j++) {
#pragma unroll
            for (int r = 0; r < 4; r++) {
                const int mrow = row0 + r0 + i * 16 + lch * 4 + r;
                const int ncol = col0 + c0 + j * 16 + lrow;
                const float v = acc[i][j][r] + bias[ncol];
                if (MODE == 0) {
                    const int t    = ncol >= 768 ? 2 : (ncol >= 384 ? 1 : 0);
                    const int rem2 = ncol - t * 384;
                    const int hh   = rem2 >> 5;
                    const int dd   = rem2 & 31;
                    const int bwin = mrow >> 9;
                    const int n    = mrow & 511;
                    bf16* dst = (t == 0) ? O0 : ((t == 1) ? O1 : O2);
                    const float vv = (t == 0) ? v * QPRE : v;   // Q prescale (log2 domain)
                    dst[(size_t)((bwin * HEADS + hh) * NTOK + n) * HD + dd] = (bf16)vv;
                } else {
                    Of[(size_t)mrow * N + ncol] = v;
                }
            }
        }
    }
}

// ---------------------------------------------------------------------------
// Flash attention (== R10): swapped QK^T, P repack in regs, XCD-chunked
// swizzle. V^T staged global->LDS via global_load_lds (linear rows); PV
// reads LDS at VSTR=520. T13 defer-max. One barrier total.
template <int BIG>
__global__ __launch_bounds__(256, 4) void attn_kernel(
    const bf16* __restrict__ Qg, const bf16* __restrict__ Kg,
    const bf16* __restrict__ Vtg, const bf16* __restrict__ posTg,
    const float* __restrict__ maskg, const bf16* __restrict__ bias2,
    const int* __restrict__ mflag, bf16* __restrict__ Og)
{
    __shared__ __align__(16) bf16 lVt[32 * VSTR];          // 33,280 B
    __shared__ __align__(16) bf16 lPos[BIG ? 16 : LPAD];

    // XCD-chunked swizzle (bijective: 3072 % 8 == 0)
    const int idx = (blockIdx.x & 7) * (NB_ATTN / 8) + (blockIdx.x >> 3);
    const int h   = idx >> 8;
    const int rem = idx & 255;
    const int b   = rem >> 2;
    const int qt  = rem & 3;
    const int g   = b & 7;
    const int tid = threadIdx.x;
    const int lane = tid & 63;
    const int wave = tid >> 6;
    const int lrow = lane & 15;
    const int lch  = lane >> 4;
    const int msk  = *mflag;

    const bf16* Qp  = Qg  + (size_t)(b * HEADS + h) * NTOK * HD;
    const bf16* Kp  = Kg  + (size_t)(b * HEADS + h) * NTOK * HD;
    const bf16* Vtp = Vtg + (size_t)(b * HEADS + h) * NTOK * HD;   // [32][512]
    const float* Mp = maskg + (size_t)g * NTOK * NTOK;
    const bf16* B2p = bias2 + (size_t)h * NTOK * NTOK;             // [q][k]

    // stage V^T rows into LDS: 8 global_load_lds per wave, one 1024B row each
    {
        const int d0 = wave * 8;
#pragma unroll
        for (int rr = 0; rr < 8; rr++) {
            const int d = d0 + rr;
            gload_lds16(Vtp + (size_t)d * NTOK + lane * 8, lVt + (size_t)d * VSTR);
        }
    }
    if (!BIG) {
        const uint4* src = (const uint4*)(posTg + h * LPAD);
        for (int i = tid; i < LPAD * 2 / 16; i += 256)
            ((uint4*)lPos)[i] = src[i];
    }
    __syncthreads();   // vmcnt(0) drain -> gload_lds complete

    const int qbase = qt * 128 + wave * 32;

    bf16x8 qf[2];
#pragma unroll
    for (int t = 0; t < 2; t++)
        qf[t] = *(const bf16x8*)(Qp + (size_t)(qbase + t * 16 + lrow) * HD + lch * 8);

    int qc0[2] = {0, 0}, qc1[2] = {0, 0}, qc2[2] = {0, 0};
    if (!BIG) {
#pragma unroll
        for (int t = 0; t < 2; t++) {
            const int q = qbase + t * 16 + lrow;
            qc0[t] = q >> 6; qc1[t] = (q >> 3) & 7; qc2[t] = q & 7;
        }
    }

    float m_i[2] = {-1e30f, -1e30f};
    float l_i[2] = {0.f, 0.f};
    f32x4 oacc[2][2];
    const f32x4 zero4 = {0.f, 0.f, 0.f, 0.f};
    oacc[0][0] = zero4; oacc[0][1] = zero4;
    oacc[1][0] = zero4; oacc[1][1] = zero4;

    for (int kt = 0; kt < 4; kt++) {
        bf16x8 apc[2][4];   // packed P, A-fragment layout, per q-tile per 32-k chunk
        float alr[2];
        bool doresc[2];

#pragma unroll
        for (int t = 0; t < 2; t++) {
            const int qrow = qbase + t * 16 + lrow;
            f32x4 sf[8];

            // bias prefetch (BIG): 8 x bf16x4, vectorized along k
            bf16x4 bld[8];
            if (BIG) {
                const bf16* brow = B2p + (size_t)qrow * NTOK + kt * 128 + lch * 4;
#pragma unroll
                for (int ct = 0; ct < 8; ct++)
                    bld[ct] = *(const bf16x4*)(brow + ct * 16);
            }

            // S^T = K @ Q^T  (C layout: row = k-token, col = q = lrow)
#pragma unroll
            for (int ct = 0; ct < 8; ct++) {
                bf16x8 kf = *(const bf16x8*)(Kp + (size_t)(kt * 128 + ct * 16 + lrow) * HD + lch * 8);
                sf[ct] = __builtin_amdgcn_mfma_f32_16x16x32_bf16(kf, qf[t], zero4, 0, 0, 0);
            }

            if (BIG) {
#pragma unroll
                for (int ct = 0; ct < 8; ct++)
#pragma unroll
                    for (int r = 0; r < 4; r++)
                        sf[ct][r] += (float)bld[ct][r];
            } else {
#pragma unroll
                for (int ct = 0; ct < 8; ct++) {
#pragma unroll
                    for (int r = 0; r < 4; r++) {
                        const int k = kt * 128 + ct * 16 + lch * 4 + r;
                        const int rpi = (qc0[t] - (k >> 6) + 7) * 225
                                      + (qc1[t] - ((k >> 3) & 7) + 7) * 15
                                      + (qc2[t] - (k & 7) + 7);
                        sf[ct][r] += (float)lPos[rpi];
                    }
                }
            }
            if (msk) {
                const float* mrow = Mp + (size_t)qrow * NTOK + kt * 128 + lch * 4;
#pragma unroll
                for (int ct = 0; ct < 8; ct++) {
                    f32x4 mv = *(const f32x4*)(mrow + ct * 16);
#pragma unroll
                    for (int r = 0; r < 4; r++)
                        sf[ct][r] = fmaf(mv[r], LOG2E, sf[ct][r]);
                }
            }

            // online softmax (base 2): in-lane tree + 2 cross-lane hops
            float px[8];
#pragma unroll
            for (int ct = 0; ct < 8; ct++)
                px[ct] = fmaxf(fmaxf(sf[ct][0], sf[ct][1]), fmaxf(sf[ct][2], sf[ct][3]));
            float mx = fmaxf(fmaxf(fmaxf(px[0], px[1]), fmaxf(px[2], px[3])),
                             fmaxf(fmaxf(px[4], px[5]), fmaxf(px[6], px[7])));
            mx = fmaxf(mx, __shfl_xor(mx, 16));
            mx = fmaxf(mx, __shfl_xor(mx, 32));

            // T13 defer-max: keep stale m while growth <= 8 (p <= 2^8, bf16-ok)
            if (__all(mx <= m_i[t] + 8.f)) {
                alr[t] = 1.f;
                doresc[t] = false;
            } else {
                const float mnew = fmaxf(m_i[t], mx);
                alr[t] = ex2(m_i[t] - mnew);
                m_i[t] = mnew;
                doresc[t] = true;
            }

            float s0 = 0.f, s1 = 0.f;
#pragma unroll
            for (int ct = 0; ct < 8; ct++) {
#pragma unroll
                for (int r = 0; r < 4; r++)
                    sf[ct][r] = ex2(sf[ct][r] - m_i[t]);
                s0 += sf[ct][0] + sf[ct][1];
                s1 += sf[ct][2] + sf[ct][3];
            }
            float ls = s0 + s1;
            ls += __shfl_xor(ls, 16);
            ls += __shfl_xor(ls, 32);
            l_i[t] = l_i[t] * alr[t] + ls;

            // pack P -> A-fragments, fully in registers (cvt_pk + permlane;
            // distinct operands — proven since R7).
#pragma unroll
            for (int c2 = 0; c2 < 4; c2++) {
                u32 a01 = cvtpk(sf[2 * c2][0],     sf[2 * c2][1]);
                u32 a23 = cvtpk(sf[2 * c2][2],     sf[2 * c2][3]);
                u32 b01 = cvtpk(sf[2 * c2 + 1][0], sf[2 * c2 + 1][1]);
                u32 b23 = cvtpk(sf[2 * c2 + 1][2], sf[2 * c2 + 1][3]);
                plswap32(a01, b01); plswap16(a01, b01);
                plswap32(a23, b23); plswap16(a23, b23);
                u32x4v w; w[0] = a01; w[1] = a23; w[2] = b01; w[3] = b23;
                apc[t][c2] = __builtin_bit_cast(bf16x8, w);
            }
        }

        // rescale O by alpha (wave-uniform skip when deferred)
#pragma unroll
        for (int t = 0; t < 2; t++) {
            if (doresc[t]) {
#pragma unroll
                for (int r = 0; r < 4; r++) {
                    const float a = __shfl(alr[t], lch * 4 + r);
                    oacc[t][0][r] *= a;
                    oacc[t][1][r] *= a;
                }
            }
        }

        // P @ V from LDS V^T
#pragma unroll
        for (int c2 = 0; c2 < 4; c2++) {
            const int mofs = kt * 128 + c2 * 32;
            bf16x8 bv0 = *(const bf16x8*)(lVt + (size_t)lrow * VSTR + mofs + lch * 8);
            bf16x8 bv1 = *(const bf16x8*)(lVt + (size_t)(16 + lrow) * VSTR + mofs + lch * 8);
#pragma unroll
            for (int t = 0; t < 2; t++) {
                oacc[t][0] = __builtin_amdgcn_mfma_f32_16x16x32_bf16(apc[t][c2], bv0, oacc[t][0], 0, 0, 0);
                oacc[t][1] = __builtin_amdgcn_mfma_f32_16x16x32_bf16(apc[t][c2], bv1, oacc[t][1], 0, 0, 0);
            }
        }
    }

#pragma unroll
    for (int t = 0; t < 2; t++) {
#pragma unroll
        for (int r = 0; r < 4; r++) {
            const float lv  = __shfl(l_i[t], lch * 4 + r);
            const float inv = 1.f / fmaxf(lv, 1e-20f);
            const int n = qbase + t * 16 + lch * 4 + r;
            bf16* orow = Og + (size_t)(b * NTOK + n) * DIMC + h * HD;
            orow[lrow]      = (bf16)(oacc[t][0][r] * inv);
            orow[16 + lrow] = (bf16)(oacc[t][1][r] * inv);
        }
    }
}

// ---------------------------------------------------------------------------
extern "C" void kernel_launch(void* const* d_in, const int* in_sizes, int n_in,
                              void* d_out, int out_size, void* d_ws, size_t ws_size,
                              hipStream_t stream)
{
    if (ws_size < WS_SMALL) return;
    const bool BIG = (ws_size >= WS_BIG);

    const float* x      = (const float*)d_in[0];
    const float* maskp  = (const float*)d_in[4];
    const float* qkv_w  = (const float*)d_in[5];
    const float* qkv_b  = (const float*)d_in[6];
    const float* proj_w = (const float*)d_in[7];
    const float* proj_b = (const float*)d_in[8];

    char* ws = (char*)d_ws;
    size_t off = 0;
    bf16* wsWqT  = (bf16*)(ws + off); off += SZ_WQT;
    bf16* wsWpT  = (bf16*)(ws + off); off += SZ_WPT;
    bf16* wsPosT = (bf16*)(ws + off); off += SZ_POST;
    int*  wsFlag = (int*)(ws + off);  off += SZ_FLAG;
    bf16* wsB2 = nullptr;
    if (BIG) {
        wsB2 = (bf16*)(ws + off); off += SZ_B2;
        off += SZ_MT;              // legacy region, keeps proven layout
    } else {
        off = 1572864;
    }
    bf16* wsQ    = (bf16*)(ws + off); off += SZ_QKV;
    bf16* wsK    = (bf16*)(ws + off); off += SZ_QKV;
    bf16* wsV    = (bf16*)(ws + off); off += SZ_QKV;
    bf16* wsAttn = (bf16*)(ws + off);
    bf16* wsXb   = wsAttn;   // x-bf16 aliases attn-out: dead before attn writes

    hipMemsetAsync(wsFlag, 0, 4, stream);

    prep_kernel<<<NB_PREP, 256, 0, stream>>>(
        x, qkv_w, proj_w, maskp,
        (const float*)d_in[9],  (const float*)d_in[10], (const float*)d_in[11],
        (const float*)d_in[12], (const float*)d_in[13], (const float*)d_in[14],
        (const float*)d_in[15], (const float*)d_in[16], (const float*)d_in[17],
        (const float*)d_in[18], (const float*)d_in[19], (const float*)d_in[20],
        (const float*)d_in[21], (const float*)d_in[22],
        wsXb, wsWqT, wsWpT, wsFlag, wsPosT);

    if (BIG)
        bias2_build_kernel<<<(HEADS * NTOK * NTOK) / 256, 256, 0, stream>>>(wsPosT, wsB2);

    // QKV: [32768 x 384] @ [384 x 1152] -> scatter Q/K/V (Q pre-scaled)
    gemm_bt<0><<<dim3(128, 9), 512, 0, stream>>>(wsXb, wsWqT, qkv_b, wsQ, wsK, wsV,
                                                 nullptr, 384, 1152);

    // V pages -> V^T in place (768 x 32KB pages)
    vt_inplace_kernel<<<NWIN * HEADS, 256, 0, stream>>>(wsV);

    if (BIG)
        attn_kernel<1><<<NB_ATTN, 256, 0, stream>>>(
            wsQ, wsK, wsV, wsPosT, maskp, wsB2, wsFlag, wsAttn);
    else
        attn_kernel<0><<<NB_ATTN, 256, 0, stream>>>(
            wsQ, wsK, wsV, wsPosT, maskp, wsB2, wsFlag, wsAttn);

    // proj: [32768 x 384] @ [384 x 384] -> d_out (fp32)
    gemm_bt<1><<<dim3(128, 3), 512, 0, stream>>>(wsAttn, wsWpT, proj_b,
                                                 nullptr, nullptr, nullptr,
                                                 (float*)d_out, 384, 384);
}